// Round 9
// baseline (214.016 us; speedup 1.0000x reference)
//
#include <hip/hip_runtime.h>

typedef __attribute__((ext_vector_type(8))) __bf16 bf16x8;
typedef __attribute__((ext_vector_type(4))) __bf16 bf16x4;
typedef __attribute__((ext_vector_type(4))) float f32x4;

typedef __attribute__((address_space(1))) void as1_void;
typedef __attribute__((address_space(3))) void as3_void;

__device__ __forceinline__ void gl_lds16(const void* g, void* l) {
    __builtin_amdgcn_global_load_lds((const as1_void*)g, (as3_void*)l, 16, 0, 0);
}

// swizzled fragment pointer for a [rows][64] bf16 LDS buffer (row = 128 B,
// 16-byte chunks XOR-swizzled by row&7 to kill bank conflicts)
__device__ __forceinline__ const bf16x8* swz(const __bf16* base, int row, int chunk) {
    return (const bf16x8*)((const char*)base + row * 128 + ((chunk ^ (row & 7)) * 16));
}

#define QSCALE (0.125f * 1.44269504f)   // 1/sqrt(64) * log2(e), folded into Wqk

// ---------------------------------------------------------------------------
// prep: convert x -> bf16; build WvT, WpT (transposed); compute
// bqv = [ (qb@Wk^T + kb)*QSCALE ; vb ] from fp32; and the fused weight GEMM
// mtb[n][i] = QSCALE * sum_b Wk[n][b]*Wq[i][b]  (fp32-staged, 64 blocks).
// Sections by blockIdx.x:
//   [0,1024)    WvT transpose tiles   [1024,2048) WpT transpose tiles
//   [2048,6144) x convert             [6144,6160) bias_q + vb
//   [6160,6224) mtb GEMM
// ---------------------------------------------------------------------------
__global__ __launch_bounds__(256) void prep_kernel(
    const float* __restrict__ x, const float* __restrict__ caw,
    const float* __restrict__ cab, const float* __restrict__ cpw,
    __bf16* __restrict__ xb, __bf16* __restrict__ wvt,
    __bf16* __restrict__ wpt, __bf16* __restrict__ mtb,
    float* __restrict__ bqv)
{
    __shared__ __align__(16) char shm[20480];
    int bid = blockIdx.x;
    int tid = threadIdx.x;
    if (bid < 1024) {                      // WvT[n][k] = caw[k][2048+n]
        float* tile = (float*)shm;
        int nt = bid >> 5, kt = bid & 31;
        int tx = tid & 31, ty = tid >> 5;  // 32 x 8
        int n0 = nt * 32, k0 = kt * 32;
#pragma unroll
        for (int i = 0; i < 4; ++i)
            tile[(ty + i * 8) * 33 + tx] = caw[(long)(k0 + ty + i * 8) * 3072 + 2048 + n0 + tx];
        __syncthreads();
#pragma unroll
        for (int i = 0; i < 4; ++i)
            wvt[(long)(n0 + ty + i * 8) * 1024 + k0 + tx] = (__bf16)tile[tx * 33 + ty + i * 8];
    } else if (bid < 2048) {               // WpT[n][k] = cpw[k][n]
        float* tile = (float*)shm;
        int v = bid - 1024;
        int nt = v >> 5, kt = v & 31;
        int tx = tid & 31, ty = tid >> 5;
        int n0 = nt * 32, k0 = kt * 32;
#pragma unroll
        for (int i = 0; i < 4; ++i)
            tile[(ty + i * 8) * 33 + tx] = cpw[(long)(k0 + ty + i * 8) * 1024 + n0 + tx];
        __syncthreads();
#pragma unroll
        for (int i = 0; i < 4; ++i)
            wpt[(long)(n0 + ty + i * 8) * 1024 + k0 + tx] = (__bf16)tile[tx * 33 + ty + i * 8];
    } else if (bid < 6144) {               // x convert
        long e = (long)(bid - 2048) * 1024 + tid * 4;
        float4 f = *(const float4*)(x + e);
        bf16x4 o = {(__bf16)f.x, (__bf16)f.y, (__bf16)f.z, (__bf16)f.w};
        *(bf16x4*)(xb + e) = o;
    } else if (bid < 6160) {               // bias_q + vb (16 blocks, 64 n each)
        int k = bid - 6144;
        int wave = tid >> 6, lane = tid & 63;
        float qv[16];
#pragma unroll
        for (int u = 0; u < 4; ++u) {
            float4 q4 = *(const float4*)(cab + u * 256 + lane * 4);
            qv[u * 4 + 0] = q4.x; qv[u * 4 + 1] = q4.y;
            qv[u * 4 + 2] = q4.z; qv[u * 4 + 3] = q4.w;
        }
        for (int i = 0; i < 16; ++i) {
            int n = k * 64 + wave * 16 + i;
            float s = 0.f;
#pragma unroll
            for (int u = 0; u < 4; ++u) {
                float4 w4 = *(const float4*)(caw + (long)n * 3072 + 1024 + u * 256 + lane * 4);
                s += w4.x * qv[u * 4 + 0] + w4.y * qv[u * 4 + 1]
                   + w4.z * qv[u * 4 + 2] + w4.w * qv[u * 4 + 3];
            }
#pragma unroll
            for (int off = 1; off < 64; off <<= 1) s += __shfl_xor(s, off);
            if (lane == 0) bqv[n] = (s + cab[1024 + n]) * QSCALE;
        }
        if (tid < 64) bqv[1024 + k * 64 + tid] = cab[2048 + k * 64 + tid];
    } else {                               // mtb GEMM (fp32-staged, BK=32)
        __bf16* Asm = (__bf16*)shm;        // [128][40]
        __bf16* Bsm = Asm + 5120;          // [128][40]
        int v = bid - 6160;
        const long m0 = (long)(v >> 3) * 128;
        const long n0 = (long)(v & 7) * 128;
        const int lane = tid & 63, wave = tid >> 6;
        const int quad = lane >> 4, l16 = lane & 15;
        const int wm = (wave >> 1) * 64, wn = (wave & 1) * 64;
        f32x4 acc[4][4] = {};
        for (int k0 = 0; k0 < 1024; k0 += 32) {
            for (int e = tid; e < 1024; e += 256) {
                int row = e >> 3, c4 = e & 7;
                float4 fa = *(const float4*)(caw + (m0 + row) * 3072 + 1024 + k0 + c4 * 4);
                float4 fb = *(const float4*)(caw + (n0 + row) * 3072 + k0 + c4 * 4);
                bf16x4 oa = {(__bf16)fa.x, (__bf16)fa.y, (__bf16)fa.z, (__bf16)fa.w};
                bf16x4 ob = {(__bf16)fb.x, (__bf16)fb.y, (__bf16)fb.z, (__bf16)fb.w};
                *(bf16x4*)(Asm + row * 40 + c4 * 4) = oa;
                *(bf16x4*)(Bsm + row * 40 + c4 * 4) = ob;
            }
            __syncthreads();
            bf16x8 af[4], bfr[4];
#pragma unroll
            for (int i = 0; i < 4; ++i)
                af[i] = *(const bf16x8*)(Asm + (wm + i * 16 + l16) * 40 + quad * 8);
#pragma unroll
            for (int j = 0; j < 4; ++j)
                bfr[j] = *(const bf16x8*)(Bsm + (wn + j * 16 + l16) * 40 + quad * 8);
#pragma unroll
            for (int i = 0; i < 4; ++i)
#pragma unroll
                for (int j = 0; j < 4; ++j)
                    acc[i][j] = __builtin_amdgcn_mfma_f32_16x16x32_bf16(af[i], bfr[j], acc[i][j], 0, 0, 0);
            __syncthreads();
        }
#pragma unroll
        for (int i = 0; i < 4; ++i) {
            long row = m0 + wm + i * 16 + quad * 4;
#pragma unroll
            for (int j = 0; j < 4; ++j) {
                int col = (int)n0 + wn + j * 16 + l16;
#pragma unroll
                for (int r = 0; r < 4; ++r)
                    mtb[(row + r) * 1024 + col] = (__bf16)(acc[i][j][r] * QSCALE);
            }
        }
    }
}

// ---------------------------------------------------------------------------
// Generic GEMM: C[M,*] = (A[M,K] x BT[N,K] + bias) * oscale.  BK = 64,
// XOR-chunk-swizzled LDS (128 B rows). NT = BN/32 16-col groups per wave.
// ---------------------------------------------------------------------------
template <bool BF16OUT, int BN>
__global__ __launch_bounds__(256) void gemm_bt(
    const __bf16* __restrict__ A, int lda,
    const __bf16* __restrict__ B, int ldb,
    const float* __restrict__ bias,
    void* __restrict__ C, int ldc, int K, float oscale)
{
    constexpr int NT = BN / 32;            // 16-col groups per wave
    __shared__ __bf16 As[128 * 64];
    __shared__ __bf16 Bs[BN * 64];
    const int tid = threadIdx.x;
    const int lane = tid & 63;
    const int wave = tid >> 6;
    const int quad = lane >> 4, l16 = lane & 15;
    const long m0 = (long)blockIdx.y * 128;
    const long n0 = (long)blockIdx.x * BN;
    const int wm = (wave >> 1) * 64, wn = (wave & 1) * (BN / 2);

    f32x4 acc[4][NT] = {};

    for (int k0 = 0; k0 < K; k0 += 64) {
#pragma unroll
        for (int c = tid; c < (128 + BN) * 8; c += 256) {
            int row = c >> 3, cc = (c & 7) ^ (row & 7);
            if (row < 128)
                gl_lds16(A + (m0 + row) * lda + k0 + cc * 8, As + c * 8);
            else
                gl_lds16(B + (n0 + row - 128) * ldb + k0 + cc * 8, Bs + (c - 1024) * 8);
        }
        __syncthreads();
#pragma unroll
        for (int kk = 0; kk < 2; ++kk) {
            bf16x8 af[4], bfr[NT];
#pragma unroll
            for (int i = 0; i < 4; ++i)
                af[i] = *swz(As, wm + i * 16 + l16, kk * 4 + quad);
#pragma unroll
            for (int j = 0; j < NT; ++j)
                bfr[j] = *swz(Bs, wn + j * 16 + l16, kk * 4 + quad);
#pragma unroll
            for (int i = 0; i < 4; ++i)
#pragma unroll
                for (int j = 0; j < NT; ++j)
                    acc[i][j] = __builtin_amdgcn_mfma_f32_16x16x32_bf16(af[i], bfr[j], acc[i][j], 0, 0, 0);
        }
        __syncthreads();
    }
#pragma unroll
    for (int i = 0; i < 4; ++i) {
        long row = m0 + wm + i * 16 + quad * 4;
#pragma unroll
        for (int j = 0; j < NT; ++j) {
            int col = (int)n0 + wn + j * 16 + l16;
            float bb = bias ? bias[col] : 0.f;
#pragma unroll
            for (int r = 0; r < 4; ++r) {
                float v = (acc[i][j][r] + bb) * oscale;
                if (BF16OUT)
                    ((__bf16*)C)[(row + r) * ldc + col] = (__bf16)v;
                else
                    ((float*)C)[(row + r) * ldc + col] = v;
            }
        }
    }
}

// ---------------------------------------------------------------------------
// gemm_qv: grid (16, 32). B = [Wqk^T ; Wv^T] (2048 rows, contiguous). BK=64.
// blockIdx.x < 8  : q-half -> Qout [4096][1024] row-major
// blockIdx.x >= 8 : v-half -> VTout [2048][2048] via in-LDS transpose.
// ---------------------------------------------------------------------------
__global__ __launch_bounds__(256) void gemm_qv(
    const __bf16* __restrict__ A,       // xb [4096][1024]
    const __bf16* __restrict__ B,       // [2048][1024]
    const float* __restrict__ bias,     // [2048]
    __bf16* __restrict__ Qout,          // [4096][1024]
    __bf16* __restrict__ VTout)         // [2048][2048]
{
    __shared__ __bf16 smem[128 * 136];  // main loop uses first 16384 elems
    __bf16* As = smem;
    __bf16* Bs = smem + 8192;
    const int tid = threadIdx.x;
    const int lane = tid & 63;
    const int wave = tid >> 6;
    const int quad = lane >> 4, l16 = lane & 15;
    const long m0 = (long)blockIdx.y * 128;
    const long n0 = (long)blockIdx.x * 128;
    const int wm = (wave >> 1) * 64, wn = (wave & 1) * 64;

    f32x4 acc[4][4] = {};

    for (int k0 = 0; k0 < 1024; k0 += 64) {
#pragma unroll
        for (int c = tid; c < 2048; c += 256) {
            int row = c >> 3, cc = (c & 7) ^ (row & 7);
            if (row < 128)
                gl_lds16(A + (m0 + row) * 1024 + k0 + cc * 8, As + c * 8);
            else
                gl_lds16(B + (n0 + row - 128) * 1024 + k0 + cc * 8, Bs + (c - 1024) * 8);
        }
        __syncthreads();
#pragma unroll
        for (int kk = 0; kk < 2; ++kk) {
            bf16x8 af[4], bfr[4];
#pragma unroll
            for (int i = 0; i < 4; ++i)
                af[i] = *swz(As, wm + i * 16 + l16, kk * 4 + quad);
#pragma unroll
            for (int j = 0; j < 4; ++j)
                bfr[j] = *swz(Bs, wn + j * 16 + l16, kk * 4 + quad);
#pragma unroll
            for (int i = 0; i < 4; ++i)
#pragma unroll
                for (int j = 0; j < 4; ++j)
                    acc[i][j] = __builtin_amdgcn_mfma_f32_16x16x32_bf16(af[i], bfr[j], acc[i][j], 0, 0, 0);
        }
        __syncthreads();
    }

    if (n0 < 1024) {
        // q-half: normal row-major store
#pragma unroll
        for (int i = 0; i < 4; ++i) {
            long row = m0 + wm + i * 16 + quad * 4;
#pragma unroll
            for (int j = 0; j < 4; ++j) {
                int col = (int)n0 + wn + j * 16 + l16;
                float bb = bias[col];
#pragma unroll
                for (int r = 0; r < 4; ++r)
                    Qout[(row + r) * 1024 + col] = (__bf16)(acc[i][j][r] + bb);
            }
        }
    } else {
        // v-half: transpose through LDS (pitch 136), coalesced V^T rows out.
        __syncthreads();
#pragma unroll
        for (int i = 0; i < 4; ++i) {
#pragma unroll
            for (int j = 0; j < 4; ++j) {
                int col = (int)n0 + wn + j * 16 + l16;
                float bb = bias[col];
                bf16x4 v;
#pragma unroll
                for (int r = 0; r < 4; ++r) v[r] = (__bf16)(acc[i][j][r] + bb);
                *(bf16x4*)(smem + (wn + j * 16 + l16) * 136 + wm + i * 16 + quad * 4) = v;
            }
        }
        __syncthreads();
        const int d0 = (int)n0 - 1024;
        const int bb = (int)(m0 >> 11);
        const int sl = (int)(m0 & 2047);
#pragma unroll
        for (int pass = 0; pass < 16; ++pass) {
            int idx = pass * 256 + tid;
            int n = idx >> 5;             // 0..127
            int mc = (idx & 31) * 4;      // 0..124
            bf16x4 v = *(const bf16x4*)(smem + n * 136 + mc);
            *(bf16x4*)(VTout + ((long)(bb * 1024 + d0 + n)) * 2048 + sl + mc) = v;
        }
    }
}

// ---------------------------------------------------------------------------
// Flash attention, no-max softmax, pair-balanced, wave-group specialized.
// grid (32, 16) x 512 threads: x = bh (XCD-local), y = pair.
// Waves 0-3 own q-tile qa strips, waves 4-7 own q-tile qb=31-qa strips;
// K/V tiles staged once per 128-kv barrier, shared by both groups.
// ---------------------------------------------------------------------------
__global__ __launch_bounds__(512) void attn_kernel(
    const __bf16* __restrict__ Q,   // [4096][1024], pre-scaled
    const __bf16* __restrict__ Xb,  // [4096][1024]
    const __bf16* __restrict__ VT,  // [2048][2048]
    __bf16* __restrict__ O)         // [4096][1024]
{
    __shared__ __bf16 Ks[2 * 8192];
    __shared__ __bf16 Vs[2 * 8192];
    __shared__ __bf16 Ps[8 * 1024];
    const int tid = threadIdx.x;
    const int lane = tid & 63;
    const int wave = tid >> 6;        // 0..7
    const int group = wave >> 2;      // 0 -> qa, 1 -> qb
    const int w4 = wave & 3;
    const int quad = lane >> 4, l16 = lane & 15;
    const int qa = blockIdx.y;        // 0..15
    const int qb = 31 - qa;           // 16..31
    const int qt = group ? qb : qa;
    const int bh = blockIdx.x;
    const int b = bh >> 4, h = bh & 15;
    const long rowbase = (long)b * 2048;

    const int s0 = tid;               // 0..511, row = s0>>3 in [0,64)
    const int c0 = ((s0 & 7) ^ ((s0 >> 3) & 7)) * 8;

    bf16x8 ones;
#pragma unroll
    for (int i = 0; i < 8; ++i) ones[i] = (__bf16)1.0f;

    // this wave's Q strip straight to registers (B-operand layout)
    bf16x8 qfr[2];
    {
        const __bf16* qp = Q + (rowbase + qt * 64 + w4 * 16 + l16) * 1024 + h * 64 + quad * 8;
        qfr[0] = *(const bf16x8*)(qp);
        qfr[1] = *(const bf16x8*)(qp + 32);
    }

    const __bf16* kp0 = Xb + (rowbase + (s0 >> 3)) * 1024 + h * 64 + c0;
    const __bf16* vp0 = VT + ((long)(b * 1024 + h * 64 + (s0 >> 3))) * 2048 + c0;

    auto stage_tile = [&](int j, int buf, int sub) {
        gl_lds16(kp0 + (long)j * 65536, Ks + buf * 8192 + sub * 4096 + s0 * 8);
        gl_lds16(vp0 + j * 64, Vs + buf * 8192 + sub * 4096 + s0 * 8);
    };
    stage_tile(0, 0, 0);
    stage_tile(1, 0, 1);

    const int nouter = (qb + 2) >> 1;     // ceil((qb+1)/2)

    f32x4 oacc[4] = {};
    f32x4 lacc = {};
    __bf16* Pw = Ps + wave * 1024;

    for (int jj = 0; jj < nouter; ++jj) {
        __syncthreads();                  // buf[jj&1] ready; prev reads done
        if (jj + 1 < nouter) {
            stage_tile(2 * jj + 2, (jj + 1) & 1, 0);
            stage_tile(2 * jj + 3, (jj + 1) & 1, 1);
        }

#pragma unroll
        for (int sub = 0; sub < 2; ++sub) {
            const int j = 2 * jj + sub;
            if (j > qt) continue;         // wave-uniform
            const __bf16* Kb = Ks + (jj & 1) * 8192 + sub * 4096;
            const __bf16* Vb = Vs + (jj & 1) * 8192 + sub * 4096;

            bf16x8 kf[2][4], vf[2][4];
#pragma unroll
            for (int kk = 0; kk < 2; ++kk)
#pragma unroll
                for (int kt = 0; kt < 4; ++kt) {
                    kf[kk][kt] = *swz(Kb, kt * 16 + l16, kk * 4 + quad);
                    vf[kk][kt] = *swz(Vb, kt * 16 + l16, kk * 4 + quad);
                }

            // S^T = K Q^T : rows = kv, cols = q (this wave's 16-q strip)
            f32x4 sacc[4] = {};
#pragma unroll
            for (int kk = 0; kk < 2; ++kk)
#pragma unroll
                for (int kt = 0; kt < 4; ++kt)
                    sacc[kt] = __builtin_amdgcn_mfma_f32_16x16x32_bf16(
                        kf[kk][kt], qfr[kk], sacc[kt], 0, 0, 0);

            // p = exp2(s); masking branch only on the diagonal tile
            if (j == qt) {
                const int qloc = w4 * 16 + l16;
#pragma unroll
                for (int kt = 0; kt < 4; ++kt) {
                    bf16x4 pk;
#pragma unroll
                    for (int r = 0; r < 4; ++r) {
                        float s = sacc[kt][r];
                        if (kt * 16 + quad * 4 + r > qloc) s = -1e30f;
                        pk[r] = (__bf16)exp2f(s);
                    }
                    *(bf16x4*)((char*)Pw + l16 * 128 +
                               (((kt * 2 + (quad >> 1)) ^ (l16 & 7)) * 16) + (quad & 1) * 8) = pk;
                }
            } else {
#pragma unroll
                for (int kt = 0; kt < 4; ++kt) {
                    bf16x4 pk;
#pragma unroll
                    for (int r = 0; r < 4; ++r)
                        pk[r] = (__bf16)exp2f(sacc[kt][r]);
                    *(bf16x4*)((char*)Pw + l16 * 128 +
                               (((kt * 2 + (quad >> 1)) ^ (l16 & 7)) * 16) + (quad & 1) * 8) = pk;
                }
            }

            // O^T += VT * P^T ; l += ones * P^T   (per-wave P buffer)
#pragma unroll
            for (int kk = 0; kk < 2; ++kk) {
                bf16x8 pf = *swz(Pw, l16, kk * 4 + quad);
                lacc = __builtin_amdgcn_mfma_f32_16x16x32_bf16(ones, pf, lacc, 0, 0, 0);
#pragma unroll
                for (int dt = 0; dt < 4; ++dt)
                    oacc[dt] = __builtin_amdgcn_mfma_f32_16x16x32_bf16(
                        vf[kk][dt], pf, oacc[dt], 0, 0, 0);
            }
        }
    }

    // epilogue: normalize (l complete in every lane) and store
    {
        float inv = 1.0f / lacc[0];
        long row = rowbase + qt * 64 + w4 * 16 + l16;
#pragma unroll
        for (int dt = 0; dt < 4; ++dt) {
            bf16x4 ov;
#pragma unroll
            for (int r = 0; r < 4; ++r) ov[r] = (__bf16)(oacc[dt][r] * inv);
            *(bf16x4*)(O + row * 1024 + h * 64 + dt * 16 + quad * 4) = ov;
        }
    }
}

// ---------------------------------------------------------------------------
extern "C" void kernel_launch(void* const* d_in, const int* in_sizes, int n_in,
                              void* d_out, int out_size, void* d_ws, size_t ws_size,
                              hipStream_t stream) {
    const float* x   = (const float*)d_in[0];
    const float* caw = (const float*)d_in[1];
    const float* cab = (const float*)d_in[2];
    const float* cpw = (const float*)d_in[3];
    const float* cpb = (const float*)d_in[4];

    char* p = (char*)d_ws;
    auto alloc = [&](size_t bytes) {
        void* r = (void*)p;
        p += (bytes + 255) & ~(size_t)255;
        return r;
    };
    __bf16* xb    = (__bf16*)alloc(4096UL * 1024 * 2);   // x bf16
    __bf16* mtb   = (__bf16*)alloc(1024UL * 1024 * 2);   // (Wq Wk^T)^T * QSCALE
    __bf16* wvt   = (__bf16*)alloc(1024UL * 1024 * 2);   // Wv^T (contiguous after mtb!)
    __bf16* wpt   = (__bf16*)alloc(1024UL * 1024 * 2);   // Wp^T
    float*  bqv   = (float*) alloc(2048UL * 4);          // [bq' scaled ; vb]
    __bf16* qbuf  = (__bf16*)alloc(4096UL * 1024 * 2);   // q (pre-scaled)
    __bf16* vt    = (__bf16*)alloc(2048UL * 2048 * 2);   // V^T per (b,h)
    __bf16* attn  = (__bf16*)alloc(4096UL * 1024 * 2);   // attention out

    // prep (incl. fused bias_q and mtb weight-GEMM)
    prep_kernel<<<6224, 256, 0, stream>>>(x, caw, cab, cpw, xb, wvt, wpt, mtb, bqv);
    // q -> qbuf, V^T -> vt (fused, single launch)
    gemm_qv<<<dim3(16, 32), 256, 0, stream>>>(xb, mtb, bqv, qbuf, vt);
    // attention (pair-balanced, wave-group specialized, 128 kv per barrier)
    attn_kernel<<<dim3(32, 16), 512, 0, stream>>>(qbuf, xb, vt, attn);
    // out = attn @ Wp + pb (fp32)
    gemm_bt<false, 64><<<dim3(16, 32), 256, 0, stream>>>(attn, 1024, wpt, 1024, cpb,
                                                         d_out, 1024, 1024, 1.0f);
    (void)in_sizes; (void)n_in; (void)out_size; (void)ws_size;
}

// Round 10
// 181.421 us; speedup vs baseline: 1.1797x; 1.1797x over previous
//
#include <hip/hip_runtime.h>

typedef __attribute__((ext_vector_type(8))) __bf16 bf16x8;
typedef __attribute__((ext_vector_type(4))) __bf16 bf16x4;
typedef __attribute__((ext_vector_type(4))) float f32x4;

typedef __attribute__((address_space(1))) void as1_void;
typedef __attribute__((address_space(3))) void as3_void;

__device__ __forceinline__ void gl_lds16(const void* g, void* l) {
    __builtin_amdgcn_global_load_lds((const as1_void*)g, (as3_void*)l, 16, 0, 0);
}

// swizzled fragment pointer for a [rows][64] bf16 LDS buffer (row = 128 B,
// 16-byte chunks XOR-swizzled by row&7 to kill bank conflicts)
__device__ __forceinline__ const bf16x8* swz(const __bf16* base, int row, int chunk) {
    return (const bf16x8*)((const char*)base + row * 128 + ((chunk ^ (row & 7)) * 16));
}

#define QSCALE (0.125f * 1.44269504f)   // 1/sqrt(64) * log2(e), folded into Wqk

// ---------------------------------------------------------------------------
// prep: convert x -> bf16; build WvT, WpT (transposed), WkN, WqN (rows),
// and compute bqv = [ (qb@Wk^T + kb)*QSCALE ; vb ] directly from fp32 inputs.
// Sections by blockIdx.x:
//   [0,1024)    WvT transpose tiles   [1024,2048) WpT transpose tiles
//   [2048,3072) WkN convert           [3072,4096) WqN convert
//   [4096,8192) x convert             [8192,8208) bias_q + vb
// ---------------------------------------------------------------------------
__global__ __launch_bounds__(256) void prep_kernel(
    const float* __restrict__ x, const float* __restrict__ caw,
    const float* __restrict__ cab, const float* __restrict__ cpw,
    __bf16* __restrict__ xb, __bf16* __restrict__ wvt,
    __bf16* __restrict__ wkn, __bf16* __restrict__ wqn,
    __bf16* __restrict__ wpt, float* __restrict__ bqv)
{
    __shared__ float tile[32 * 33];
    int bid = blockIdx.x;
    int tid = threadIdx.x;
    if (bid < 1024) {                      // WvT[n][k] = caw[k][2048+n]
        int nt = bid >> 5, kt = bid & 31;
        int tx = tid & 31, ty = tid >> 5;  // 32 x 8
        int n0 = nt * 32, k0 = kt * 32;
#pragma unroll
        for (int i = 0; i < 4; ++i)
            tile[(ty + i * 8) * 33 + tx] = caw[(long)(k0 + ty + i * 8) * 3072 + 2048 + n0 + tx];
        __syncthreads();
#pragma unroll
        for (int i = 0; i < 4; ++i)
            wvt[(long)(n0 + ty + i * 8) * 1024 + k0 + tx] = (__bf16)tile[tx * 33 + ty + i * 8];
    } else if (bid < 2048) {               // WpT[n][k] = cpw[k][n]
        int v = bid - 1024;
        int nt = v >> 5, kt = v & 31;
        int tx = tid & 31, ty = tid >> 5;
        int n0 = nt * 32, k0 = kt * 32;
#pragma unroll
        for (int i = 0; i < 4; ++i)
            tile[(ty + i * 8) * 33 + tx] = cpw[(long)(k0 + ty + i * 8) * 1024 + n0 + tx];
        __syncthreads();
#pragma unroll
        for (int i = 0; i < 4; ++i)
            wpt[(long)(n0 + ty + i * 8) * 1024 + k0 + tx] = (__bf16)tile[tx * 33 + ty + i * 8];
    } else if (bid < 3072) {               // WkN[n][k] = caw[n][1024+k]
        int e = (bid - 2048) * 1024 + tid * 4;
        int n = e >> 10, k = e & 1023;
        float4 f = *(const float4*)(caw + (long)n * 3072 + 1024 + k);
        bf16x4 o = {(__bf16)f.x, (__bf16)f.y, (__bf16)f.z, (__bf16)f.w};
        *(bf16x4*)(wkn + e) = o;
    } else if (bid < 4096) {               // WqN[i][b] = caw[i][b]
        int e = (bid - 3072) * 1024 + tid * 4;
        int n = e >> 10, k = e & 1023;
        float4 f = *(const float4*)(caw + (long)n * 3072 + k);
        bf16x4 o = {(__bf16)f.x, (__bf16)f.y, (__bf16)f.z, (__bf16)f.w};
        *(bf16x4*)(wqn + e) = o;
    } else if (bid < 8192) {               // x convert
        long e = (long)(bid - 4096) * 1024 + tid * 4;
        float4 f = *(const float4*)(x + e);
        bf16x4 o = {(__bf16)f.x, (__bf16)f.y, (__bf16)f.z, (__bf16)f.w};
        *(bf16x4*)(xb + e) = o;
    } else {                               // bias_q + vb (16 blocks, 64 n each)
        int k = bid - 8192;
        int wave = tid >> 6, lane = tid & 63;
        float qv[16];
#pragma unroll
        for (int u = 0; u < 4; ++u) {
            float4 q4 = *(const float4*)(cab + u * 256 + lane * 4);
            qv[u * 4 + 0] = q4.x; qv[u * 4 + 1] = q4.y;
            qv[u * 4 + 2] = q4.z; qv[u * 4 + 3] = q4.w;
        }
        for (int i = 0; i < 16; ++i) {
            int n = k * 64 + wave * 16 + i;
            float s = 0.f;
#pragma unroll
            for (int u = 0; u < 4; ++u) {
                float4 w4 = *(const float4*)(caw + (long)n * 3072 + 1024 + u * 256 + lane * 4);
                s += w4.x * qv[u * 4 + 0] + w4.y * qv[u * 4 + 1]
                   + w4.z * qv[u * 4 + 2] + w4.w * qv[u * 4 + 3];
            }
#pragma unroll
            for (int off = 1; off < 64; off <<= 1) s += __shfl_xor(s, off);
            if (lane == 0) bqv[n] = (s + cab[1024 + n]) * QSCALE;
        }
        if (tid < 64) bqv[1024 + k * 64 + tid] = cab[2048 + k * 64 + tid];
    }
}

// ---------------------------------------------------------------------------
// Generic GEMM: C[M,*] = (A[M,K] x BT[N,K] + bias) * oscale.  BK = 64,
// XOR-chunk-swizzled LDS (128 B rows). NT = BN/32 16-col groups per wave.
// ---------------------------------------------------------------------------
template <bool BF16OUT, int BN>
__global__ __launch_bounds__(256) void gemm_bt(
    const __bf16* __restrict__ A, int lda,
    const __bf16* __restrict__ B, int ldb,
    const float* __restrict__ bias,
    void* __restrict__ C, int ldc, int K, float oscale)
{
    constexpr int NT = BN / 32;            // 16-col groups per wave
    __shared__ __bf16 As[128 * 64];
    __shared__ __bf16 Bs[BN * 64];
    const int tid = threadIdx.x;
    const int lane = tid & 63;
    const int wave = tid >> 6;
    const int quad = lane >> 4, l16 = lane & 15;
    const long m0 = (long)blockIdx.y * 128;
    const long n0 = (long)blockIdx.x * BN;
    const int wm = (wave >> 1) * 64, wn = (wave & 1) * (BN / 2);

    f32x4 acc[4][NT] = {};

    for (int k0 = 0; k0 < K; k0 += 64) {
#pragma unroll
        for (int c = tid; c < (128 + BN) * 8; c += 256) {
            int row = c >> 3, cc = (c & 7) ^ (row & 7);
            if (row < 128)
                gl_lds16(A + (m0 + row) * lda + k0 + cc * 8, As + c * 8);
            else
                gl_lds16(B + (n0 + row - 128) * ldb + k0 + cc * 8, Bs + (c - 1024) * 8);
        }
        __syncthreads();
#pragma unroll
        for (int kk = 0; kk < 2; ++kk) {
            bf16x8 af[4], bfr[NT];
#pragma unroll
            for (int i = 0; i < 4; ++i)
                af[i] = *swz(As, wm + i * 16 + l16, kk * 4 + quad);
#pragma unroll
            for (int j = 0; j < NT; ++j)
                bfr[j] = *swz(Bs, wn + j * 16 + l16, kk * 4 + quad);
#pragma unroll
            for (int i = 0; i < 4; ++i)
#pragma unroll
                for (int j = 0; j < NT; ++j)
                    acc[i][j] = __builtin_amdgcn_mfma_f32_16x16x32_bf16(af[i], bfr[j], acc[i][j], 0, 0, 0);
        }
        __syncthreads();
    }
#pragma unroll
    for (int i = 0; i < 4; ++i) {
        long row = m0 + wm + i * 16 + quad * 4;
#pragma unroll
        for (int j = 0; j < NT; ++j) {
            int col = (int)n0 + wn + j * 16 + l16;
            float bb = bias ? bias[col] : 0.f;
#pragma unroll
            for (int r = 0; r < 4; ++r) {
                float v = (acc[i][j][r] + bb) * oscale;
                if (BF16OUT)
                    ((__bf16*)C)[(row + r) * ldc + col] = (__bf16)v;
                else
                    ((float*)C)[(row + r) * ldc + col] = v;
            }
        }
    }
}

// ---------------------------------------------------------------------------
// gemm_qv: grid (16, 32). B = [Wqk^T ; Wv^T] (2048 rows, contiguous). BK=64.
// blockIdx.x < 8  : q-half -> Qout [4096][1024] row-major
// blockIdx.x >= 8 : v-half -> VTout [2048][2048] via in-LDS transpose.
// ---------------------------------------------------------------------------
__global__ __launch_bounds__(256) void gemm_qv(
    const __bf16* __restrict__ A,       // xb [4096][1024]
    const __bf16* __restrict__ B,       // [2048][1024]
    const float* __restrict__ bias,     // [2048]
    __bf16* __restrict__ Qout,          // [4096][1024]
    __bf16* __restrict__ VTout)         // [2048][2048]
{
    __shared__ __bf16 smem[128 * 136];  // main loop uses first 16384 elems
    __bf16* As = smem;
    __bf16* Bs = smem + 8192;
    const int tid = threadIdx.x;
    const int lane = tid & 63;
    const int wave = tid >> 6;
    const int quad = lane >> 4, l16 = lane & 15;
    const long m0 = (long)blockIdx.y * 128;
    const long n0 = (long)blockIdx.x * 128;
    const int wm = (wave >> 1) * 64, wn = (wave & 1) * 64;

    f32x4 acc[4][4] = {};

    for (int k0 = 0; k0 < 1024; k0 += 64) {
#pragma unroll
        for (int c = tid; c < 2048; c += 256) {
            int row = c >> 3, cc = (c & 7) ^ (row & 7);
            if (row < 128)
                gl_lds16(A + (m0 + row) * 1024 + k0 + cc * 8, As + c * 8);
            else
                gl_lds16(B + (n0 + row - 128) * 1024 + k0 + cc * 8, Bs + (c - 1024) * 8);
        }
        __syncthreads();
#pragma unroll
        for (int kk = 0; kk < 2; ++kk) {
            bf16x8 af[4], bfr[4];
#pragma unroll
            for (int i = 0; i < 4; ++i)
                af[i] = *swz(As, wm + i * 16 + l16, kk * 4 + quad);
#pragma unroll
            for (int j = 0; j < 4; ++j)
                bfr[j] = *swz(Bs, wn + j * 16 + l16, kk * 4 + quad);
#pragma unroll
            for (int i = 0; i < 4; ++i)
#pragma unroll
                for (int j = 0; j < 4; ++j)
                    acc[i][j] = __builtin_amdgcn_mfma_f32_16x16x32_bf16(af[i], bfr[j], acc[i][j], 0, 0, 0);
        }
        __syncthreads();
    }

    if (n0 < 1024) {
        // q-half: normal row-major store
#pragma unroll
        for (int i = 0; i < 4; ++i) {
            long row = m0 + wm + i * 16 + quad * 4;
#pragma unroll
            for (int j = 0; j < 4; ++j) {
                int col = (int)n0 + wn + j * 16 + l16;
                float bb = bias[col];
#pragma unroll
                for (int r = 0; r < 4; ++r)
                    Qout[(row + r) * 1024 + col] = (__bf16)(acc[i][j][r] + bb);
            }
        }
    } else {
        // v-half: transpose through LDS (pitch 136), coalesced V^T rows out.
        __syncthreads();
#pragma unroll
        for (int i = 0; i < 4; ++i) {
#pragma unroll
            for (int j = 0; j < 4; ++j) {
                int col = (int)n0 + wn + j * 16 + l16;
                float bb = bias[col];
                bf16x4 v;
#pragma unroll
                for (int r = 0; r < 4; ++r) v[r] = (__bf16)(acc[i][j][r] + bb);
                *(bf16x4*)(smem + (wn + j * 16 + l16) * 136 + wm + i * 16 + quad * 4) = v;
            }
        }
        __syncthreads();
        const int d0 = (int)n0 - 1024;
        const int bb = (int)(m0 >> 11);
        const int sl = (int)(m0 & 2047);
#pragma unroll
        for (int pass = 0; pass < 16; ++pass) {
            int idx = pass * 256 + tid;
            int n = idx >> 5;             // 0..127
            int mc = (idx & 31) * 4;      // 0..124
            bf16x4 v = *(const bf16x4*)(smem + n * 136 + mc);
            *(bf16x4*)(VTout + ((long)(bb * 1024 + d0 + n)) * 2048 + sl + mc) = v;
        }
    }
}

// ---------------------------------------------------------------------------
// Flash attention, no-max softmax, pair-balanced, wave-group specialized.
// grid (32, 16) x 512 threads: x = bh (XCD-local), y = pair.
// Waves 0-3 own q-tile qa strips, waves 4-7 own q-tile qb=31-qa strips;
// K/V tiles staged once per 128-kv barrier, shared by both groups.
// ---------------------------------------------------------------------------
__global__ __launch_bounds__(512) void attn_kernel(
    const __bf16* __restrict__ Q,   // [4096][1024], pre-scaled
    const __bf16* __restrict__ Xb,  // [4096][1024]
    const __bf16* __restrict__ VT,  // [2048][2048]
    __bf16* __restrict__ O)         // [4096][1024]
{
    __shared__ __bf16 Ks[2 * 8192];
    __shared__ __bf16 Vs[2 * 8192];
    __shared__ __bf16 Ps[8 * 1024];
    const int tid = threadIdx.x;
    const int lane = tid & 63;
    const int wave = tid >> 6;        // 0..7
    const int group = wave >> 2;      // 0 -> qa, 1 -> qb
    const int w4 = wave & 3;
    const int quad = lane >> 4, l16 = lane & 15;
    const int qa = blockIdx.y;        // 0..15
    const int qb = 31 - qa;           // 16..31
    const int qt = group ? qb : qa;
    const int bh = blockIdx.x;
    const int b = bh >> 4, h = bh & 15;
    const long rowbase = (long)b * 2048;

    const int s0 = tid;               // 0..511, row = s0>>3 in [0,64)
    const int c0 = ((s0 & 7) ^ ((s0 >> 3) & 7)) * 8;

    bf16x8 ones;
#pragma unroll
    for (int i = 0; i < 8; ++i) ones[i] = (__bf16)1.0f;

    // this wave's Q strip straight to registers (B-operand layout)
    bf16x8 qfr[2];
    {
        const __bf16* qp = Q + (rowbase + qt * 64 + w4 * 16 + l16) * 1024 + h * 64 + quad * 8;
        qfr[0] = *(const bf16x8*)(qp);
        qfr[1] = *(const bf16x8*)(qp + 32);
    }

    const __bf16* kp0 = Xb + (rowbase + (s0 >> 3)) * 1024 + h * 64 + c0;
    const __bf16* vp0 = VT + ((long)(b * 1024 + h * 64 + (s0 >> 3))) * 2048 + c0;

    auto stage_tile = [&](int j, int buf, int sub) {
        gl_lds16(kp0 + (long)j * 65536, Ks + buf * 8192 + sub * 4096 + s0 * 8);
        gl_lds16(vp0 + j * 64, Vs + buf * 8192 + sub * 4096 + s0 * 8);
    };
    stage_tile(0, 0, 0);
    stage_tile(1, 0, 1);

    const int nouter = (qb + 2) >> 1;     // ceil((qb+1)/2)

    f32x4 oacc[4] = {};
    f32x4 lacc = {};
    __bf16* Pw = Ps + wave * 1024;

    for (int jj = 0; jj < nouter; ++jj) {
        __syncthreads();                  // buf[jj&1] ready; prev reads done
        if (jj + 1 < nouter) {
            stage_tile(2 * jj + 2, (jj + 1) & 1, 0);
            stage_tile(2 * jj + 3, (jj + 1) & 1, 1);
        }

#pragma unroll
        for (int sub = 0; sub < 2; ++sub) {
            const int j = 2 * jj + sub;
            if (j > qt) continue;         // wave-uniform
            const __bf16* Kb = Ks + (jj & 1) * 8192 + sub * 4096;
            const __bf16* Vb = Vs + (jj & 1) * 8192 + sub * 4096;

            bf16x8 kf[2][4], vf[2][4];
#pragma unroll
            for (int kk = 0; kk < 2; ++kk)
#pragma unroll
                for (int kt = 0; kt < 4; ++kt) {
                    kf[kk][kt] = *swz(Kb, kt * 16 + l16, kk * 4 + quad);
                    vf[kk][kt] = *swz(Vb, kt * 16 + l16, kk * 4 + quad);
                }

            // S^T = K Q^T : rows = kv, cols = q (this wave's 16-q strip)
            f32x4 sacc[4] = {};
#pragma unroll
            for (int kk = 0; kk < 2; ++kk)
#pragma unroll
                for (int kt = 0; kt < 4; ++kt)
                    sacc[kt] = __builtin_amdgcn_mfma_f32_16x16x32_bf16(
                        kf[kk][kt], qfr[kk], sacc[kt], 0, 0, 0);

            // p = exp2(s); masking branch only on the diagonal tile
            if (j == qt) {
                const int qloc = w4 * 16 + l16;
#pragma unroll
                for (int kt = 0; kt < 4; ++kt) {
                    bf16x4 pk;
#pragma unroll
                    for (int r = 0; r < 4; ++r) {
                        float s = sacc[kt][r];
                        if (kt * 16 + quad * 4 + r > qloc) s = -1e30f;
                        pk[r] = (__bf16)exp2f(s);
                    }
                    *(bf16x4*)((char*)Pw + l16 * 128 +
                               (((kt * 2 + (quad >> 1)) ^ (l16 & 7)) * 16) + (quad & 1) * 8) = pk;
                }
            } else {
#pragma unroll
                for (int kt = 0; kt < 4; ++kt) {
                    bf16x4 pk;
#pragma unroll
                    for (int r = 0; r < 4; ++r)
                        pk[r] = (__bf16)exp2f(sacc[kt][r]);
                    *(bf16x4*)((char*)Pw + l16 * 128 +
                               (((kt * 2 + (quad >> 1)) ^ (l16 & 7)) * 16) + (quad & 1) * 8) = pk;
                }
            }

            // O^T += VT * P^T ; l += ones * P^T   (per-wave P buffer)
#pragma unroll
            for (int kk = 0; kk < 2; ++kk) {
                bf16x8 pf = *swz(Pw, l16, kk * 4 + quad);
                lacc = __builtin_amdgcn_mfma_f32_16x16x32_bf16(ones, pf, lacc, 0, 0, 0);
#pragma unroll
                for (int dt = 0; dt < 4; ++dt)
                    oacc[dt] = __builtin_amdgcn_mfma_f32_16x16x32_bf16(
                        vf[kk][dt], pf, oacc[dt], 0, 0, 0);
            }
        }
    }

    // epilogue: normalize (l complete in every lane) and store
    {
        float inv = 1.0f / lacc[0];
        long row = rowbase + qt * 64 + w4 * 16 + l16;
#pragma unroll
        for (int dt = 0; dt < 4; ++dt) {
            bf16x4 ov;
#pragma unroll
            for (int r = 0; r < 4; ++r) ov[r] = (__bf16)(oacc[dt][r] * inv);
            *(bf16x4*)(O + row * 1024 + h * 64 + dt * 16 + quad * 4) = ov;
        }
    }
}

// ---------------------------------------------------------------------------
extern "C" void kernel_launch(void* const* d_in, const int* in_sizes, int n_in,
                              void* d_out, int out_size, void* d_ws, size_t ws_size,
                              hipStream_t stream) {
    const float* x   = (const float*)d_in[0];
    const float* caw = (const float*)d_in[1];
    const float* cab = (const float*)d_in[2];
    const float* cpw = (const float*)d_in[3];
    const float* cpb = (const float*)d_in[4];

    char* p = (char*)d_ws;
    auto alloc = [&](size_t bytes) {
        void* r = (void*)p;
        p += (bytes + 255) & ~(size_t)255;
        return r;
    };
    __bf16* xb    = (__bf16*)alloc(4096UL * 1024 * 2);   // x bf16
    __bf16* mtb   = (__bf16*)alloc(1024UL * 1024 * 2);   // (Wq Wk^T)^T * QSCALE
    __bf16* wvt   = (__bf16*)alloc(1024UL * 1024 * 2);   // Wv^T (contiguous after mtb!)
    __bf16* wkn   = (__bf16*)alloc(1024UL * 1024 * 2);   // Wk rows
    __bf16* wqn   = (__bf16*)alloc(1024UL * 1024 * 2);   // Wq rows
    __bf16* wpt   = (__bf16*)alloc(1024UL * 1024 * 2);   // Wp^T
    float*  bqv   = (float*) alloc(2048UL * 4);          // [bq' scaled ; vb]
    __bf16* qbuf  = (__bf16*)alloc(4096UL * 1024 * 2);   // q (pre-scaled)
    __bf16* vt    = (__bf16*)alloc(2048UL * 2048 * 2);   // V^T per (b,h)
    __bf16* attn  = (__bf16*)alloc(4096UL * 1024 * 2);   // attention out

    prep_kernel<<<8208, 256, 0, stream>>>(x, caw, cab, cpw, xb, wvt, wkn, wqn, wpt, bqv);

    // Wqk^T = (Wk Wq^T) * QSCALE   [n][i]   (256 blocks = 1/CU)
    gemm_bt<true, 32><<<dim3(32, 8), 256, 0, stream>>>(wkn, 1024, wqn, 1024, nullptr,
                                                       (void*)mtb, 1024, 1024, QSCALE);
    // q -> qbuf, V^T -> vt (fused, single launch)
    gemm_qv<<<dim3(16, 32), 256, 0, stream>>>(xb, mtb, bqv, qbuf, vt);
    // attention (pair-balanced, wave-group specialized, 128 kv per barrier)
    attn_kernel<<<dim3(32, 16), 512, 0, stream>>>(qbuf, xb, vt, attn);
    // out = attn @ Wp + pb (fp32)
    gemm_bt<false, 64><<<dim3(16, 32), 256, 0, stream>>>(attn, 1024, wpt, 1024, cpb,
                                                         d_out, 1024, 1024, 1.0f);
    (void)in_sizes; (void)n_in; (void)out_size; (void)ws_size;
}